// Round 1
// baseline (11343.975 us; speedup 1.0000x reference)
//
#include <hip/hip_runtime.h>
#include <math.h>

#define B_    4
#define CIN_  64
#define COUT_ 64
#define DD    8
#define HH    48
#define WW    48
#define NN    (DD * HH * WW)   // 18432
#define KK    27
#define OCT   108              // 81 offset channels + 27 mask channels

// ---------------------------------------------------------------------------
// Kernel 1: fused 108-channel 3x3x3 conv (offsets + mask logits), pad=1.
// Block: 128 threads, handles 8 consecutive W positions (same b,z,y).
// Thread t (< 108) computes output channel t for all 8 positions.
// Input halo (64 ch x 3 x 3 x 10) staged in LDS.
// ---------------------------------------------------------------------------
__global__ __launch_bounds__(128) void conv108_kernel(
    const float* __restrict__ x, const float* __restrict__ w_off,
    const float* __restrict__ b_off, const float* __restrict__ w_mask,
    const float* __restrict__ b_mask, float* __restrict__ conv_out)
{
  const int tid = threadIdx.x;
  const int xt  = blockIdx.x * 8;       // W tile base
  const int y   = blockIdx.y;
  const int bz  = blockIdx.z;
  const int b   = bz / DD;
  const int z   = bz % DD;

  __shared__ float xs[CIN_ * 90];       // [cin][dz*3+dy][xc(0..9)]

  for (int i = tid; i < CIN_ * 90; i += 128) {
    int cin = i / 90;
    int r   = i % 90;
    int dz  = r / 30;
    int rr  = r % 30;
    int dy  = rr / 10;
    int xc  = rr % 10;
    int zz = z - 1 + dz, yy = y - 1 + dy, xx = xt - 1 + xc;
    float v = 0.f;
    if (zz >= 0 && zz < DD && yy >= 0 && yy < HH && xx >= 0 && xx < WW)
      v = x[(((size_t)b * CIN_ + cin) * DD + zz) * (HH * WW) + yy * WW + xx];
    xs[i] = v;
  }
  __syncthreads();

  if (tid < OCT) {
    const float* wp;
    float bv;
    if (tid < 81) { wp = w_off  + (size_t)tid * CIN_ * 27;        bv = b_off[tid]; }
    else          { wp = w_mask + (size_t)(tid - 81) * CIN_ * 27; bv = b_mask[tid - 81]; }

    float acc[8];
#pragma unroll
    for (int j = 0; j < 8; ++j) acc[j] = bv;

    for (int cin = 0; cin < CIN_; ++cin) {
      const float* wc = wp + cin * 27;
      const float* xc = xs + cin * 90;
#pragma unroll
      for (int p = 0; p < 27; ++p) {
        const int dz = p / 9, dy = (p / 3) % 3, dx = p % 3;
        const float wv = wc[p];
        const float* xr = xc + (dz * 3 + dy) * 10 + dx;   // broadcast LDS reads
#pragma unroll
        for (int j = 0; j < 8; ++j) acc[j] += wv * xr[j];
      }
    }

    const int nbase = (z * HH + y) * WW + xt;
    float* op = conv_out + ((size_t)b * OCT + tid) * NN + nbase;
#pragma unroll
    for (int j = 0; j < 8; ++j) op[j] = acc[j];
  }
}

// ---------------------------------------------------------------------------
// Kernel 2: softmax over the K=27 mask logits (channels 81..107), in place.
// One thread per (b, n). Loads/stores coalesced across n for each k.
// ---------------------------------------------------------------------------
__global__ void softmax_kernel(float* __restrict__ conv_out)
{
  const int i = blockIdx.x * blockDim.x + threadIdx.x;
  if (i >= B_ * NN) return;
  const int b = i / NN, n = i % NN;
  float* mp = conv_out + ((size_t)b * OCT + 81) * NN + n;

  float v[KK];
  float mx = -1e30f;
#pragma unroll
  for (int k = 0; k < KK; ++k) { v[k] = mp[(size_t)k * NN]; mx = fmaxf(mx, v[k]); }
  float s = 0.f;
#pragma unroll
  for (int k = 0; k < KK; ++k) { v[k] = expf(v[k] - mx); s += v[k]; }
  const float inv = 1.f / s;
#pragma unroll
  for (int k = 0; k < KK; ++k) mp[(size_t)k * NN] = v[k] * inv;
}

// ---------------------------------------------------------------------------
// Trilinear sample with zero padding (matches reference semantics).
// ---------------------------------------------------------------------------
__device__ __forceinline__ float trilinear(const float* __restrict__ xc,
                                           float pz, float py, float px)
{
  const float z0f = floorf(pz), y0f = floorf(py), x0f = floorf(px);
  const int z0 = (int)z0f, y0 = (int)y0f, x0 = (int)x0f;
  const float fz = pz - z0f, fy = py - y0f, fx = px - x0f;
  const float wz[2] = {1.f - fz, fz};
  const float wy[2] = {1.f - fy, fy};
  const float wx[2] = {1.f - fx, fx};
  float r = 0.f;
#pragma unroll
  for (int dz = 0; dz < 2; ++dz) {
    const int zi = z0 + dz;
    if (zi < 0 || zi >= DD) continue;
#pragma unroll
    for (int dy = 0; dy < 2; ++dy) {
      const int yi = y0 + dy;
      if (yi < 0 || yi >= HH) continue;
#pragma unroll
      for (int dx = 0; dx < 2; ++dx) {
        const int xi = x0 + dx;
        if (xi < 0 || xi >= WW) continue;
        r += xc[(zi * HH + yi) * WW + xi] * (wz[dz] * wy[dy] * wx[dx]);
      }
    }
  }
  return r;
}

// ---------------------------------------------------------------------------
// Kernel 3: deformable aggregation + 64x64 matvec per tap.
// Block: 64 threads, 4 consecutive positions.
//   Phase A: thread = cin  -> trilinear sample * mask -> LDS
//   Phase B: thread = cout -> accumulate w[cout][cin][k] * s[cin]
// ---------------------------------------------------------------------------
__global__ __launch_bounds__(64) void deform_main_kernel(
    const float* __restrict__ x, const float* __restrict__ conv_out,
    const float* __restrict__ weight, const float* __restrict__ bias,
    float* __restrict__ out)
{
  const int tid   = threadIdx.x;
  const int gbase = blockIdx.x * 4;
  const int b     = gbase / NN;
  const int n0    = gbase % NN;     // 4 consecutive n, same b (NN % 4 == 0)

  __shared__ float smem[4][CIN_];
  float acc[4] = {0.f, 0.f, 0.f, 0.f};

  const float* xb = x + ((size_t)b * CIN_ + tid) * NN;   // channel 'tid'
  const float* cb = conv_out + (size_t)b * OCT * NN;

  for (int k = 0; k < KK; ++k) {
    const int kz = k / 9, ky = (k / 3) % 3, kx = k % 3;

#pragma unroll
    for (int j = 0; j < 4; ++j) {
      const int n  = n0 + j;
      const int z  = n / (HH * WW);
      const int y  = (n / WW) % HH;
      const int xp = n % WW;
      const float oz = cb[(size_t)(3 * k + 0) * NN + n];
      const float oy = cb[(size_t)(3 * k + 1) * NN + n];
      const float ox = cb[(size_t)(3 * k + 2) * NN + n];
      const float m  = cb[(size_t)(81 + k)    * NN + n];
      const float pz = (float)(z - 1 + kz) + oz;
      const float py = (float)(y - 1 + ky) + oy;
      const float px = (float)(xp - 1 + kx) + ox;
      smem[j][tid] = trilinear(xb, pz, py, px) * m;
    }
    __syncthreads();

    const float* wk = weight + (size_t)tid * CIN_ * 27 + k;  // [cout=tid][cin][k]
    for (int cin = 0; cin < CIN_; ++cin) {
      const float wv = wk[cin * 27];
#pragma unroll
      for (int j = 0; j < 4; ++j) acc[j] += wv * smem[j][cin];
    }
    __syncthreads();
  }

  const float bv = bias[tid];
  float* op = out + ((size_t)b * COUT_ + tid) * NN + n0;
#pragma unroll
  for (int j = 0; j < 4; ++j) op[j] = acc[j] + bv;
}

// ---------------------------------------------------------------------------
extern "C" void kernel_launch(void* const* d_in, const int* in_sizes, int n_in,
                              void* d_out, int out_size, void* d_ws, size_t ws_size,
                              hipStream_t stream)
{
  const float* x      = (const float*)d_in[0];
  const float* w_off  = (const float*)d_in[1];
  const float* b_off  = (const float*)d_in[2];
  const float* w_mask = (const float*)d_in[3];
  const float* b_mask = (const float*)d_in[4];
  const float* weight = (const float*)d_in[5];
  const float* bias   = (const float*)d_in[6];
  float* out      = (float*)d_out;
  float* conv_out = (float*)d_ws;   // B*108*N floats = 31.85 MB

  dim3 g1(WW / 8, HH, B_ * DD);
  conv108_kernel<<<g1, 128, 0, stream>>>(x, w_off, b_off, w_mask, b_mask, conv_out);
  softmax_kernel<<<(B_ * NN + 255) / 256, 256, 0, stream>>>(conv_out);
  deform_main_kernel<<<(B_ * NN) / 4, 64, 0, stream>>>(x, conv_out, weight, bias, out);
}

// Round 2
// 1577.125 us; speedup vs baseline: 7.1928x; 7.1928x over previous
//
#include <hip/hip_runtime.h>
#include <math.h>

#define B_    4
#define CIN_  64
#define COUT_ 64
#define DD    8
#define HH    48
#define WW    48
#define NN    (DD * HH * WW)   // 18432
#define KK    27
#define OCT   108              // 81 offset channels + 27 mask channels

typedef float f32x2 __attribute__((ext_vector_type(2)));
typedef float f32x4 __attribute__((ext_vector_type(4)));

// ---------------------------------------------------------------------------
// Transpose x[b][c][n] -> xT[b][n][c]  (LDS-tiled, both sides coalesced)
// Block: 256 threads, tile = 64 n x 64 c.
// ---------------------------------------------------------------------------
__global__ __launch_bounds__(256) void transpose_x_kernel(
    const float* __restrict__ x, float* __restrict__ xT)
{
  const int tid = threadIdx.x;
  const int n0  = blockIdx.x * 64;
  const int b   = blockIdx.y;
  __shared__ float tile[64][65];

  for (int i = tid; i < 4096; i += 256) {
    const int c  = i >> 6;
    const int nl = i & 63;
    tile[c][nl] = x[((size_t)(b * CIN_ + c)) * NN + n0 + nl];
  }
  __syncthreads();
  for (int i = tid; i < 4096; i += 256) {
    const int nl = i >> 6;
    const int c  = i & 63;
    xT[((size_t)(b * NN + n0 + nl)) * CIN_ + c] = tile[c][nl];
  }
}

// ---------------------------------------------------------------------------
// Transpose weight[cout][cin][k] -> wT[k][cin][cout]   (27*64*64 = 110592)
// ---------------------------------------------------------------------------
__global__ __launch_bounds__(256) void transpose_w_kernel(
    const float* __restrict__ weight, float* __restrict__ wT)
{
  const int o = blockIdx.x * 256 + threadIdx.x;   // grid sized exactly
  const int co = o & 63;
  const int ci = (o >> 6) & 63;
  const int k  = o >> 12;
  wT[o] = weight[(size_t)(co * CIN_ + ci) * KK + k];
}

// ---------------------------------------------------------------------------
// Kernel 1: fused 108-channel 3x3x3 conv (offsets + mask logits), pad=1.
// (unchanged from round 1 — passing; optimize next round)
// ---------------------------------------------------------------------------
__global__ __launch_bounds__(128) void conv108_kernel(
    const float* __restrict__ x, const float* __restrict__ w_off,
    const float* __restrict__ b_off, const float* __restrict__ w_mask,
    const float* __restrict__ b_mask, float* __restrict__ conv_out)
{
  const int tid = threadIdx.x;
  const int xt  = blockIdx.x * 8;
  const int y   = blockIdx.y;
  const int bz  = blockIdx.z;
  const int b   = bz / DD;
  const int z   = bz % DD;

  __shared__ float xs[CIN_ * 90];

  for (int i = tid; i < CIN_ * 90; i += 128) {
    int cin = i / 90;
    int r   = i % 90;
    int dz  = r / 30;
    int rr  = r % 30;
    int dy  = rr / 10;
    int xc  = rr % 10;
    int zz = z - 1 + dz, yy = y - 1 + dy, xx = xt - 1 + xc;
    float v = 0.f;
    if (zz >= 0 && zz < DD && yy >= 0 && yy < HH && xx >= 0 && xx < WW)
      v = x[(((size_t)b * CIN_ + cin) * DD + zz) * (HH * WW) + yy * WW + xx];
    xs[i] = v;
  }
  __syncthreads();

  if (tid < OCT) {
    const float* wp;
    float bv;
    if (tid < 81) { wp = w_off  + (size_t)tid * CIN_ * 27;        bv = b_off[tid]; }
    else          { wp = w_mask + (size_t)(tid - 81) * CIN_ * 27; bv = b_mask[tid - 81]; }

    float acc[8];
#pragma unroll
    for (int j = 0; j < 8; ++j) acc[j] = bv;

    for (int cin = 0; cin < CIN_; ++cin) {
      const float* wc = wp + cin * 27;
      const float* xc = xs + cin * 90;
#pragma unroll
      for (int p = 0; p < 27; ++p) {
        const int dz = p / 9, dy = (p / 3) % 3, dx = p % 3;
        const float wv = wc[p];
        const float* xr = xc + (dz * 3 + dy) * 10 + dx;
#pragma unroll
        for (int j = 0; j < 8; ++j) acc[j] += wv * xr[j];
      }
    }

    const int nbase = (z * HH + y) * WW + xt;
    float* op = conv_out + ((size_t)b * OCT + tid) * NN + nbase;
#pragma unroll
    for (int j = 0; j < 8; ++j) op[j] = acc[j];
  }
}

// ---------------------------------------------------------------------------
// Kernel 2: softmax over K=27 mask logits (channels 81..107), in place.
// ---------------------------------------------------------------------------
__global__ void softmax_kernel(float* __restrict__ conv_out)
{
  const int i = blockIdx.x * blockDim.x + threadIdx.x;
  if (i >= B_ * NN) return;
  const int b = i / NN, n = i % NN;
  float* mp = conv_out + ((size_t)b * OCT + 81) * NN + n;

  float v[KK];
  float mx = -1e30f;
#pragma unroll
  for (int k = 0; k < KK; ++k) { v[k] = mp[(size_t)k * NN]; mx = fmaxf(mx, v[k]); }
  float s = 0.f;
#pragma unroll
  for (int k = 0; k < KK; ++k) { v[k] = expf(v[k] - mx); s += v[k]; }
  const float inv = 1.f / s;
#pragma unroll
  for (int k = 0; k < KK; ++k) mp[(size_t)k * NN] = v[k] * inv;
}

// ---------------------------------------------------------------------------
// Kernel 3: deformable aggregation + 64x64 matvec per tap.
// Block: 256 threads = 4 waves. Wave handles 16 consecutive W positions
// (16-aligned, WW%16==0 -> z,y constant per wave, x = x0+j).
// Phase A: lane = cin. Branch-free trilinear gather from xT (coalesced:
//          64 lanes read 64 consecutive floats per corner). s -> LDS (b128).
// Phase B: lane = cout. Packed-f32 matvec, weights from wT (coalesced, L2).
// ---------------------------------------------------------------------------
__global__ __launch_bounds__(256) void deform_main_kernel(
    const float* __restrict__ xT, const float* __restrict__ conv_out,
    const float* __restrict__ wT, const float* __restrict__ bias,
    float* __restrict__ out)
{
  const int tid  = threadIdx.x;
  const int wid  = tid >> 6;
  const int lane = tid & 63;

  const int gpos = (blockIdx.x * 4 + wid) * 16;
  const int b    = gpos / NN;
  const int n0   = gpos % NN;
  const int z    = n0 / (HH * WW);
  const int y    = (n0 / WW) % HH;
  const int x0   = n0 % WW;

  const float* cb  = conv_out + (size_t)b * OCT * NN;
  const float* xTb = xT + (size_t)b * NN * CIN_;

  __shared__ float s[4][64][20];   // [wave][cin][16 pos + pad] (80B rows, 16B aligned)

  f32x2 acc[8];
#pragma unroll
  for (int p = 0; p < 8; ++p) acc[p] = (f32x2){0.f, 0.f};

#pragma unroll 1
  for (int k = 0; k < KK; ++k) {
    const int kz = k / 9;
    const int kr = k - kz * 9;
    const int ky = kr / 3;
    const int kx = kr - ky * 3;
    const float bzf = (float)(z - 1 + kz);
    const float byf = (float)(y - 1 + ky);
    const float bxf = (float)(x0 - 1 + kx);

    // ---- Phase A: lane = cin ----
#pragma unroll 1
    for (int jg = 0; jg < 4; ++jg) {
      f32x4 sv;
#pragma unroll
      for (int jj = 0; jj < 4; ++jj) {
        const int j = jg * 4 + jj;
        const int n = n0 + j;
        const float oz = cb[(size_t)(3 * k + 0) * NN + n];
        const float oy = cb[(size_t)(3 * k + 1) * NN + n];
        const float ox = cb[(size_t)(3 * k + 2) * NN + n];
        const float m  = cb[(size_t)(81 + k)    * NN + n];

        const float pz = bzf + oz;
        const float py = byf + oy;
        const float px = bxf + (float)j + ox;

        const float zf = floorf(pz); const float fz = pz - zf; const int z0 = (int)zf;
        const float yf = floorf(py); const float fy = py - yf; const int y0 = (int)yf;
        const float xf = floorf(px); const float fx = px - xf; const int xi0 = (int)xf;

        float wz0 = ((unsigned)z0       < DD) ? (1.f - fz) : 0.f;
        float wz1 = ((unsigned)(z0 + 1) < DD) ? fz         : 0.f;
        float wy0 = ((unsigned)y0       < HH) ? (1.f - fy) : 0.f;
        float wy1 = ((unsigned)(y0 + 1) < HH) ? fy         : 0.f;
        float wx0 = ((unsigned)xi0      < WW) ? (1.f - fx) : 0.f;
        float wx1 = ((unsigned)(xi0 + 1)< WW) ? fx         : 0.f;

        const int z0c = min(max(z0, 0),     DD - 1);
        const int z1c = min(max(z0 + 1, 0), DD - 1);
        const int y0c = min(max(y0, 0),     HH - 1);
        const int y1c = min(max(y0 + 1, 0), HH - 1);
        const int x0c = min(max(xi0, 0),    WW - 1);
        const int x1c = min(max(xi0 + 1, 0),WW - 1);

        const int r00 = (z0c * HH + y0c) * WW;
        const int r01 = (z0c * HH + y1c) * WW;
        const int r10 = (z1c * HH + y0c) * WW;
        const int r11 = (z1c * HH + y1c) * WW;
        const float w00 = wz0 * wy0, w01 = wz0 * wy1;
        const float w10 = wz1 * wy0, w11 = wz1 * wy1;

        float acc_s;
        acc_s  = (w00 * wx0) * xTb[((r00 + x0c) << 6) + lane];
        acc_s += (w00 * wx1) * xTb[((r00 + x1c) << 6) + lane];
        acc_s += (w01 * wx0) * xTb[((r01 + x0c) << 6) + lane];
        acc_s += (w01 * wx1) * xTb[((r01 + x1c) << 6) + lane];
        acc_s += (w10 * wx0) * xTb[((r10 + x0c) << 6) + lane];
        acc_s += (w10 * wx1) * xTb[((r10 + x1c) << 6) + lane];
        acc_s += (w11 * wx0) * xTb[((r11 + x0c) << 6) + lane];
        acc_s += (w11 * wx1) * xTb[((r11 + x1c) << 6) + lane];
        sv[jj] = acc_s * m;
      }
      *(f32x4*)(&s[wid][lane][jg * 4]) = sv;   // ds_write_b128
    }
    __syncthreads();

    // ---- Phase B: lane = cout ----
    const float* wk = wT + k * (CIN_ * COUT_) + lane;
#pragma unroll 4
    for (int ci = 0; ci < CIN_; ++ci) {
      const float wv = wk[ci << 6];
      const f32x4* sp = (const f32x4*)(&s[wid][ci][0]);
      const f32x4 s0 = sp[0], s1 = sp[1], s2 = sp[2], s3 = sp[3];
      acc[0] += (f32x2){s0.x, s0.y} * wv;
      acc[1] += (f32x2){s0.z, s0.w} * wv;
      acc[2] += (f32x2){s1.x, s1.y} * wv;
      acc[3] += (f32x2){s1.z, s1.w} * wv;
      acc[4] += (f32x2){s2.x, s2.y} * wv;
      acc[5] += (f32x2){s2.z, s2.w} * wv;
      acc[6] += (f32x2){s3.x, s3.y} * wv;
      acc[7] += (f32x2){s3.z, s3.w} * wv;
    }
    __syncthreads();
  }

  const float bv = bias[lane];
  float* op = out + ((size_t)(b * COUT_ + lane)) * NN + n0;
#pragma unroll
  for (int p = 0; p < 4; ++p) {
    f32x4 o;
    o.x = acc[2 * p].x + bv;
    o.y = acc[2 * p].y + bv;
    o.z = acc[2 * p + 1].x + bv;
    o.w = acc[2 * p + 1].y + bv;
    *(f32x4*)(op + p * 4) = o;
  }
}

// ---------------------------------------------------------------------------
extern "C" void kernel_launch(void* const* d_in, const int* in_sizes, int n_in,
                              void* d_out, int out_size, void* d_ws, size_t ws_size,
                              hipStream_t stream)
{
  const float* x      = (const float*)d_in[0];
  const float* w_off  = (const float*)d_in[1];
  const float* b_off  = (const float*)d_in[2];
  const float* w_mask = (const float*)d_in[3];
  const float* b_mask = (const float*)d_in[4];
  const float* weight = (const float*)d_in[5];
  const float* bias   = (const float*)d_in[6];
  float* out = (float*)d_out;

  // Workspace layout (floats):
  //   conv_out : B*108*N          = 7,962,624  (31.85 MB)
  //   xT       : B*N*64           = 4,718,592  (18.87 MB)
  //   wT       : 27*64*64         =   110,592  ( 0.44 MB)
  float* conv_out = (float*)d_ws;
  float* xT       = conv_out + (size_t)B_ * OCT * NN;
  float* wT       = xT + (size_t)B_ * NN * CIN_;

  dim3 gtx(NN / 64, B_);
  transpose_x_kernel<<<gtx, 256, 0, stream>>>(x, xT);
  transpose_w_kernel<<<(KK * CIN_ * COUT_) / 256, 256, 0, stream>>>(weight, wT);

  dim3 g1(WW / 8, HH, B_ * DD);
  conv108_kernel<<<g1, 128, 0, stream>>>(x, w_off, b_off, w_mask, b_mask, conv_out);
  softmax_kernel<<<(B_ * NN + 255) / 256, 256, 0, stream>>>(conv_out);

  deform_main_kernel<<<(B_ * NN) / 64, 256, 0, stream>>>(xT, conv_out, wT, bias, out);
}

// Round 3
// 895.349 us; speedup vs baseline: 12.6699x; 1.7615x over previous
//
#include <hip/hip_runtime.h>
#include <hip/hip_bf16.h>
#include <math.h>

#define B_    4
#define CIN_  64
#define COUT_ 64
#define DD    8
#define HH    48
#define WW    48
#define HW2   (HH * WW)        // 2304
#define NN    (DD * HH * WW)   // 18432
#define KK    27
#define OCT   108              // 81 offset channels + 27 mask channels

typedef float f32x2 __attribute__((ext_vector_type(2)));
typedef float f32x4 __attribute__((ext_vector_type(4)));
typedef __bf16 bf16x8 __attribute__((ext_vector_type(8)));
typedef __hip_bfloat16 bf16_t;

// ---------------------------------------------------------------------------
// Zero-page init (16 B is enough for one OOB A-fragment; write 128 B).
// ---------------------------------------------------------------------------
__global__ void zp_init_kernel(bf16_t* __restrict__ zp)
{
  zp[threadIdx.x] = __float2bfloat16(0.f);
}

// ---------------------------------------------------------------------------
// Transpose x[b][c][n] -> xTbf[b][n][c] in bf16 (LDS-tiled, coalesced).
// ---------------------------------------------------------------------------
__global__ __launch_bounds__(256) void transpose_x_kernel(
    const float* __restrict__ x, bf16_t* __restrict__ xTbf)
{
  const int tid = threadIdx.x;
  const int n0  = blockIdx.x * 64;
  const int b   = blockIdx.y;
  __shared__ float tile[64][65];

  for (int i = tid; i < 4096; i += 256) {
    const int c  = i >> 6;
    const int nl = i & 63;
    tile[c][nl] = x[((size_t)(b * CIN_ + c)) * NN + n0 + nl];
  }
  __syncthreads();
  for (int i = tid; i < 4096; i += 256) {
    const int nl = i >> 6;
    const int c  = i & 63;
    xTbf[((size_t)(b * NN + n0 + nl)) * CIN_ + c] = __float2bfloat16(tile[c][nl]);
  }
}

// ---------------------------------------------------------------------------
// Transpose weight[cout][cin][k] -> wT[k][cin][cout] (fp32, for deform).
// ---------------------------------------------------------------------------
__global__ __launch_bounds__(256) void transpose_w_kernel(
    const float* __restrict__ weight, float* __restrict__ wT)
{
  const int o = blockIdx.x * 256 + threadIdx.x;
  const int co = o & 63;
  const int ci = (o >> 6) & 63;
  const int k  = o >> 12;
  wT[o] = weight[(size_t)(co * CIN_ + ci) * KK + k];
}

// ---------------------------------------------------------------------------
// Build fused conv weights wB[k][ch(112 pad)][cin] in bf16.
// ch<81: w_off, 81..107: w_mask, 108..111: zero.
// ---------------------------------------------------------------------------
__global__ __launch_bounds__(256) void wb_build_kernel(
    const float* __restrict__ w_off, const float* __restrict__ w_mask,
    bf16_t* __restrict__ wB)
{
  const int o  = blockIdx.x * 256 + threadIdx.x;   // 27*112*64 = 193536 exact
  const int ci = o & 63;
  const int ch = (o >> 6) % 112;
  const int k  = o / (112 * 64);
  float v = 0.f;
  if (ch < 81)       v = w_off[((size_t)ch * CIN_ + ci) * KK + k];
  else if (ch < 108) v = w_mask[((size_t)(ch - 81) * CIN_ + ci) * KK + k];
  wB[o] = __float2bfloat16(v);
}

// ---------------------------------------------------------------------------
// Kernel 1: fused 108-ch 3x3x3 conv via MFMA (implicit GEMM per tap).
// One wave computes a 32(pos) x 112(ch) tile; K = 64 cin per tap, 27 taps.
// A frags from global xTbf (zero-page for OOB taps), B frags from global wB.
// Both operands filled with the same [row][8 contiguous k @ 8*(l>>4)] rule:
// any within-frag k-permutation of the true HW layout cancels between A and B.
// Output: convT[b][n][108] fp32 (+bias).
// ---------------------------------------------------------------------------
__global__ __launch_bounds__(256) void conv108_mfma_kernel(
    const bf16_t* __restrict__ xTbf, const bf16_t* __restrict__ wB,
    const float* __restrict__ b_off, const float* __restrict__ b_mask,
    const bf16_t* __restrict__ zp, float* __restrict__ convT)
{
  const int tid  = threadIdx.x;
  const int wave = tid >> 6;
  const int lane = tid & 63;
  const int lg   = lane >> 4;
  const int lr   = lane & 15;

  const int gw = blockIdx.x * 4 + wave;       // 0..2303
  const int b  = gw / 576;
  const int n0 = (gw % 576) * 32;

  // decode the two m-fragment row positions this lane loads A for
  int zj[2], yj[2], xj[2];
#pragma unroll
  for (int mf = 0; mf < 2; ++mf) {
    const int n   = n0 + 16 * mf + lr;
    const int z   = n / HW2;
    const int rem = n - z * HW2;
    const int y   = rem / WW;
    zj[mf] = z; yj[mf] = y; xj[mf] = rem - y * WW;
  }

  f32x4 acc[2][7];
#pragma unroll
  for (int mf = 0; mf < 2; ++mf)
#pragma unroll
    for (int nf = 0; nf < 7; ++nf) acc[mf][nf] = (f32x4){0.f, 0.f, 0.f, 0.f};

#pragma unroll 3
  for (int k = 0; k < KK; ++k) {
    const int kz = k / 9;
    const int kr = k - kz * 9;
    const int ky = kr / 3;
    const int kx = kr - ky * 3;

    // A fragments (per-lane base pointer; OOB -> zero page)
    const bf16_t* ab[2];
#pragma unroll
    for (int mf = 0; mf < 2; ++mf) {
      const int zz = zj[mf] + kz - 1;
      const int yy = yj[mf] + ky - 1;
      const int xx = xj[mf] + kx - 1;
      const bool v = ((unsigned)zz < (unsigned)DD) &
                     ((unsigned)yy < (unsigned)HH) &
                     ((unsigned)xx < (unsigned)WW);
      ab[mf] = v ? (xTbf + ((size_t)b * NN + (zz * HH + yy) * WW + xx) * CIN_)
                 : zp;
    }
    bf16x8 afr[2][2];
#pragma unroll
    for (int mf = 0; mf < 2; ++mf)
#pragma unroll
      for (int t = 0; t < 2; ++t)
        afr[mf][t] = *(const bf16x8*)(ab[mf] + 32 * t + 8 * lg);

    // B fragments + MFMAs
    const bf16_t* wk = wB + (size_t)k * (112 * 64) + lr * 64 + 8 * lg;
#pragma unroll
    for (int nf = 0; nf < 7; ++nf) {
      const bf16x8 b0 = *(const bf16x8*)(wk + nf * 1024);
      const bf16x8 b1 = *(const bf16x8*)(wk + nf * 1024 + 32);
      acc[0][nf] = __builtin_amdgcn_mfma_f32_16x16x32_bf16(afr[0][0], b0, acc[0][nf], 0, 0, 0);
      acc[1][nf] = __builtin_amdgcn_mfma_f32_16x16x32_bf16(afr[1][0], b0, acc[1][nf], 0, 0, 0);
      acc[0][nf] = __builtin_amdgcn_mfma_f32_16x16x32_bf16(afr[0][1], b1, acc[0][nf], 0, 0, 0);
      acc[1][nf] = __builtin_amdgcn_mfma_f32_16x16x32_bf16(afr[1][1], b1, acc[1][nf], 0, 0, 0);
    }
  }

  // epilogue: bias + store (C/D layout: col = l&15, row = 4*(l>>4)+r)
  float bv[7];
#pragma unroll
  for (int nf = 0; nf < 7; ++nf) {
    const int ch = 16 * nf + lr;
    bv[nf] = (ch < 81) ? b_off[ch] : ((ch < 108) ? b_mask[ch - 81] : 0.f);
  }
#pragma unroll
  for (int mf = 0; mf < 2; ++mf)
#pragma unroll
    for (int nf = 0; nf < 7; ++nf) {
      const int ch = 16 * nf + lr;
      if (ch < 108) {
#pragma unroll
        for (int r = 0; r < 4; ++r) {
          const int row = n0 + 16 * mf + 4 * lg + r;
          convT[((size_t)b * NN + row) * OCT + ch] = acc[mf][nf][r] + bv[nf];
        }
      }
    }
}

// ---------------------------------------------------------------------------
// Kernel 2: softmax over K=27 mask logits, convT[bn][81..107], in place.
// ---------------------------------------------------------------------------
__global__ __launch_bounds__(256) void softmaxT_kernel(float* __restrict__ convT)
{
  const int i = blockIdx.x * 256 + threadIdx.x;   // 73728 exact
  float* p = convT + (size_t)i * OCT + 81;

  float v[KK];
  float mx = -1e30f;
#pragma unroll
  for (int k = 0; k < KK; ++k) { v[k] = p[k]; mx = fmaxf(mx, v[k]); }
  float s = 0.f;
#pragma unroll
  for (int k = 0; k < KK; ++k) { v[k] = expf(v[k] - mx); s += v[k]; }
  const float inv = 1.f / s;
#pragma unroll
  for (int k = 0; k < KK; ++k) p[k] = v[k] * inv;
}

// ---------------------------------------------------------------------------
// Kernel 3: deformable aggregation + 64x64 matvec per tap.
// Block: 256 threads = 4 waves; wave = 16 consecutive W positions.
// Phase A: lane = cin, gather bf16 x (coalesced), fp32 trilinear -> LDS.
// Phase B: lane = cout, packed-f32 matvec from LDS, weights from wT (L2).
// ---------------------------------------------------------------------------
__global__ __launch_bounds__(256) void deform_main_kernel(
    const bf16_t* __restrict__ xTbf, const float* __restrict__ convT,
    const float* __restrict__ wT, const float* __restrict__ bias,
    float* __restrict__ out)
{
  const int tid  = threadIdx.x;
  const int wid  = tid >> 6;
  const int lane = tid & 63;

  const int gpos = (blockIdx.x * 4 + wid) * 16;
  const int b    = gpos / NN;
  const int n0   = gpos % NN;
  const int z    = n0 / HW2;
  const int y    = (n0 / WW) % HH;
  const int x0   = n0 % WW;

  const float*  cbT = convT + (size_t)b * NN * OCT;
  const bf16_t* xTb = xTbf + (size_t)b * NN * CIN_;

  __shared__ float s[4][64][20];

  f32x2 acc[8];
#pragma unroll
  for (int p = 0; p < 8; ++p) acc[p] = (f32x2){0.f, 0.f};

#pragma unroll 1
  for (int k = 0; k < KK; ++k) {
    const int kz = k / 9;
    const int kr = k - kz * 9;
    const int ky = kr / 3;
    const int kx = kr - ky * 3;
    const float bzf = (float)(z - 1 + kz);
    const float byf = (float)(y - 1 + ky);
    const float bxf = (float)(x0 - 1 + kx);

    // ---- Phase A: lane = cin ----
#pragma unroll 1
    for (int jg = 0; jg < 4; ++jg) {
      f32x4 sv;
#pragma unroll
      for (int jj = 0; jj < 4; ++jj) {
        const int j = jg * 4 + jj;
        const int n = n0 + j;
        const float* cp = cbT + (size_t)n * OCT;
        const float oz = cp[3 * k + 0];
        const float oy = cp[3 * k + 1];
        const float ox = cp[3 * k + 2];
        const float m  = cp[81 + k];

        const float pz = bzf + oz;
        const float py = byf + oy;
        const float px = bxf + (float)j + ox;

        const float zf = floorf(pz); const float fz = pz - zf; const int z0 = (int)zf;
        const float yf = floorf(py); const float fy = py - yf; const int y0 = (int)yf;
        const float xf = floorf(px); const float fx = px - xf; const int xi0 = (int)xf;

        const float wz0 = ((unsigned)z0        < DD) ? (1.f - fz) : 0.f;
        const float wz1 = ((unsigned)(z0 + 1)  < DD) ? fz         : 0.f;
        const float wy0 = ((unsigned)y0        < HH) ? (1.f - fy) : 0.f;
        const float wy1 = ((unsigned)(y0 + 1)  < HH) ? fy         : 0.f;
        const float wx0 = ((unsigned)xi0       < WW) ? (1.f - fx) : 0.f;
        const float wx1 = ((unsigned)(xi0 + 1) < WW) ? fx         : 0.f;

        const int z0c = min(max(z0, 0),      DD - 1);
        const int z1c = min(max(z0 + 1, 0),  DD - 1);
        const int y0c = min(max(y0, 0),      HH - 1);
        const int y1c = min(max(y0 + 1, 0),  HH - 1);
        const int x0c = min(max(xi0, 0),     WW - 1);
        const int x1c = min(max(xi0 + 1, 0), WW - 1);

        const int r00 = (z0c * HH + y0c) * WW;
        const int r01 = (z0c * HH + y1c) * WW;
        const int r10 = (z1c * HH + y0c) * WW;
        const int r11 = (z1c * HH + y1c) * WW;
        const float w00 = wz0 * wy0, w01 = wz0 * wy1;
        const float w10 = wz1 * wy0, w11 = wz1 * wy1;

        float a;
        a  = (w00 * wx0) * __bfloat162float(xTb[((r00 + x0c) << 6) + lane]);
        a += (w00 * wx1) * __bfloat162float(xTb[((r00 + x1c) << 6) + lane]);
        a += (w01 * wx0) * __bfloat162float(xTb[((r01 + x0c) << 6) + lane]);
        a += (w01 * wx1) * __bfloat162float(xTb[((r01 + x1c) << 6) + lane]);
        a += (w10 * wx0) * __bfloat162float(xTb[((r10 + x0c) << 6) + lane]);
        a += (w10 * wx1) * __bfloat162float(xTb[((r10 + x1c) << 6) + lane]);
        a += (w11 * wx0) * __bfloat162float(xTb[((r11 + x0c) << 6) + lane]);
        a += (w11 * wx1) * __bfloat162float(xTb[((r11 + x1c) << 6) + lane]);
        sv[jj] = a * m;
      }
      *(f32x4*)(&s[wid][lane][jg * 4]) = sv;
    }
    __syncthreads();

    // ---- Phase B: lane = cout ----
    const float* wk = wT + k * (CIN_ * COUT_) + lane;
#pragma unroll 4
    for (int ci = 0; ci < CIN_; ++ci) {
      const float wv = wk[ci << 6];
      const f32x4* sp = (const f32x4*)(&s[wid][ci][0]);
      const f32x4 s0 = sp[0], s1 = sp[1], s2 = sp[2], s3 = sp[3];
      acc[0] += (f32x2){s0.x, s0.y} * wv;
      acc[1] += (f32x2){s0.z, s0.w} * wv;
      acc[2] += (f32x2){s1.x, s1.y} * wv;
      acc[3] += (f32x2){s1.z, s1.w} * wv;
      acc[4] += (f32x2){s2.x, s2.y} * wv;
      acc[5] += (f32x2){s2.z, s2.w} * wv;
      acc[6] += (f32x2){s3.x, s3.y} * wv;
      acc[7] += (f32x2){s3.z, s3.w} * wv;
    }
    __syncthreads();
  }

  const float bv = bias[lane];
  float* op = out + ((size_t)(b * COUT_ + lane)) * NN + n0;
#pragma unroll
  for (int p = 0; p < 4; ++p) {
    f32x4 o;
    o.x = acc[2 * p].x + bv;
    o.y = acc[2 * p].y + bv;
    o.z = acc[2 * p + 1].x + bv;
    o.w = acc[2 * p + 1].y + bv;
    *(f32x4*)(op + p * 4) = o;
  }
}

// ---------------------------------------------------------------------------
extern "C" void kernel_launch(void* const* d_in, const int* in_sizes, int n_in,
                              void* d_out, int out_size, void* d_ws, size_t ws_size,
                              hipStream_t stream)
{
  const float* x      = (const float*)d_in[0];
  const float* w_off  = (const float*)d_in[1];
  const float* b_off  = (const float*)d_in[2];
  const float* w_mask = (const float*)d_in[3];
  const float* b_mask = (const float*)d_in[4];
  const float* weight = (const float*)d_in[5];
  const float* bias   = (const float*)d_in[6];
  float* out = (float*)d_out;

  // Workspace layout (bytes, all 16B-aligned):
  //   convT : B*N*108 fp32   = 31,850,496
  //   xTbf  : B*N*64  bf16   =  9,437,184
  //   wT    : 27*64*64 fp32  =    442,368
  //   wB    : 27*112*64 bf16 =    387,072
  //   zp    : 128 B zeros
  // total ~42.1 MB
  char* ws = (char*)d_ws;
  float*  convT = (float*)ws;
  bf16_t* xTbf  = (bf16_t*)(ws + 31850496);
  float*  wT    = (float*)(ws + 31850496 + 9437184);
  bf16_t* wB    = (bf16_t*)(ws + 31850496 + 9437184 + 442368);
  bf16_t* zp    = (bf16_t*)(ws + 31850496 + 9437184 + 442368 + 387072);

  zp_init_kernel<<<1, 64, 0, stream>>>(zp);
  dim3 gtx(NN / 64, B_);
  transpose_x_kernel<<<gtx, 256, 0, stream>>>(x, xTbf);
  transpose_w_kernel<<<(KK * CIN_ * COUT_) / 256, 256, 0, stream>>>(weight, wT);
  wb_build_kernel<<<(KK * 112 * 64) / 256, 256, 0, stream>>>(w_off, w_mask, wB);

  conv108_mfma_kernel<<<576, 256, 0, stream>>>(xTbf, wB, b_off, b_mask, zp, convT);
  softmaxT_kernel<<<(B_ * NN) / 256, 256, 0, stream>>>(convT);
  deform_main_kernel<<<(B_ * NN) / 64, 256, 0, stream>>>(xTbf, convT, wT, bias, out);
}

// Round 4
// 390.466 us; speedup vs baseline: 29.0524x; 2.2930x over previous
//
#include <hip/hip_runtime.h>
#include <hip/hip_bf16.h>
#include <math.h>

#define B_    4
#define CIN_  64
#define COUT_ 64
#define DD    8
#define HH    48
#define WW    48
#define HW2   (HH * WW)        // 2304
#define NN    (DD * HH * WW)   // 18432
#define KK    27
#define OCT   108              // 81 offset + 27 mask channels

typedef float f32x2 __attribute__((ext_vector_type(2)));
typedef float f32x4 __attribute__((ext_vector_type(4)));
typedef unsigned int u32x4 __attribute__((ext_vector_type(4)));
typedef __bf16 bf16x8 __attribute__((ext_vector_type(8)));
typedef __hip_bfloat16 bf16_t;

__device__ __forceinline__ float bflo(unsigned int u) {
  return __uint_as_float(u << 16);
}
__device__ __forceinline__ float bfhi(unsigned int u) {
  return __uint_as_float(u & 0xffff0000u);
}

// ---------------------------------------------------------------------------
// Zero-page init.
// ---------------------------------------------------------------------------
__global__ void zp_init_kernel(bf16_t* __restrict__ zp)
{
  zp[threadIdx.x] = __float2bfloat16(0.f);
}

// ---------------------------------------------------------------------------
// Transpose x[b][c][n] -> xTbf[b][n][c] in bf16.
// ---------------------------------------------------------------------------
__global__ __launch_bounds__(256) void transpose_x_kernel(
    const float* __restrict__ x, bf16_t* __restrict__ xTbf)
{
  const int tid = threadIdx.x;
  const int n0  = blockIdx.x * 64;
  const int b   = blockIdx.y;
  __shared__ float tile[64][65];

  for (int i = tid; i < 4096; i += 256) {
    const int c  = i >> 6;
    const int nl = i & 63;
    tile[c][nl] = x[((size_t)(b * CIN_ + c)) * NN + n0 + nl];
  }
  __syncthreads();
  for (int i = tid; i < 4096; i += 256) {
    const int nl = i >> 6;
    const int c  = i & 63;
    xTbf[((size_t)(b * NN + n0 + nl)) * CIN_ + c] = __float2bfloat16(tile[c][nl]);
  }
}

// ---------------------------------------------------------------------------
// Conv weights wB[k][ch(112 pad)][cin] bf16 (offset+mask fused).
// ---------------------------------------------------------------------------
__global__ __launch_bounds__(256) void wb_build_kernel(
    const float* __restrict__ w_off, const float* __restrict__ w_mask,
    bf16_t* __restrict__ wB)
{
  const int o  = blockIdx.x * 256 + threadIdx.x;   // 27*112*64
  const int ci = o & 63;
  const int ch = (o >> 6) % 112;
  const int k  = o / (112 * 64);
  float v = 0.f;
  if (ch < 81)       v = w_off[((size_t)ch * CIN_ + ci) * KK + k];
  else if (ch < 108) v = w_mask[((size_t)(ch - 81) * CIN_ + ci) * KK + k];
  wB[o] = __float2bfloat16(v);
}

// ---------------------------------------------------------------------------
// Deform weights wBd[k][cout][cin] bf16.
// ---------------------------------------------------------------------------
__global__ __launch_bounds__(256) void wbd_build_kernel(
    const float* __restrict__ weight, bf16_t* __restrict__ wBd)
{
  const int o  = blockIdx.x * 256 + threadIdx.x;   // 27*64*64 = 110592
  const int ci = o & 63;
  const int co = (o >> 6) & 63;
  const int k  = o >> 12;
  wBd[o] = __float2bfloat16(weight[((size_t)co * CIN_ + ci) * KK + k]);
}

// ---------------------------------------------------------------------------
// Kernel 1: fused 108-ch 3x3x3 conv via MFMA (implicit GEMM per tap).
// Output layout: convT[b][n][k*4 + {0:oz,1:oy,2:ox,3:mask-logit}] fp32.
// ---------------------------------------------------------------------------
__global__ __launch_bounds__(256) void conv108_mfma_kernel(
    const bf16_t* __restrict__ xTbf, const bf16_t* __restrict__ wB,
    const float* __restrict__ b_off, const float* __restrict__ b_mask,
    const bf16_t* __restrict__ zp, float* __restrict__ convT)
{
  const int bid  = (blockIdx.x % 8) * 72 + blockIdx.x / 8;   // XCD swizzle (576=8*72)
  const int tid  = threadIdx.x;
  const int wave = tid >> 6;
  const int lane = tid & 63;
  const int lg   = lane >> 4;
  const int lr   = lane & 15;

  const int gw = bid * 4 + wave;              // 0..2303
  const int b  = gw / 576;
  const int n0 = (gw % 576) * 32;

  int zj[2], yj[2], xj[2];
#pragma unroll
  for (int mf = 0; mf < 2; ++mf) {
    const int n   = n0 + 16 * mf + lr;
    const int z   = n / HW2;
    const int rem = n - z * HW2;
    const int y   = rem / WW;
    zj[mf] = z; yj[mf] = y; xj[mf] = rem - y * WW;
  }

  f32x4 acc[2][7];
#pragma unroll
  for (int mf = 0; mf < 2; ++mf)
#pragma unroll
    for (int nf = 0; nf < 7; ++nf) acc[mf][nf] = (f32x4){0.f, 0.f, 0.f, 0.f};

#pragma unroll 3
  for (int k = 0; k < KK; ++k) {
    const int kz = k / 9;
    const int kr = k - kz * 9;
    const int ky = kr / 3;
    const int kx = kr - ky * 3;

    const bf16_t* ab[2];
#pragma unroll
    for (int mf = 0; mf < 2; ++mf) {
      const int zz = zj[mf] + kz - 1;
      const int yy = yj[mf] + ky - 1;
      const int xx = xj[mf] + kx - 1;
      const bool v = ((unsigned)zz < (unsigned)DD) &
                     ((unsigned)yy < (unsigned)HH) &
                     ((unsigned)xx < (unsigned)WW);
      ab[mf] = v ? (xTbf + ((size_t)b * NN + (zz * HH + yy) * WW + xx) * CIN_)
                 : zp;
    }
    bf16x8 afr[2][2];
#pragma unroll
    for (int mf = 0; mf < 2; ++mf)
#pragma unroll
      for (int t = 0; t < 2; ++t)
        afr[mf][t] = *(const bf16x8*)(ab[mf] + 32 * t + 8 * lg);

    const bf16_t* wk = wB + (size_t)k * (112 * 64) + lr * 64 + 8 * lg;
#pragma unroll
    for (int nf = 0; nf < 7; ++nf) {
      const bf16x8 b0 = *(const bf16x8*)(wk + nf * 1024);
      const bf16x8 b1 = *(const bf16x8*)(wk + nf * 1024 + 32);
      acc[0][nf] = __builtin_amdgcn_mfma_f32_16x16x32_bf16(afr[0][0], b0, acc[0][nf], 0, 0, 0);
      acc[1][nf] = __builtin_amdgcn_mfma_f32_16x16x32_bf16(afr[1][0], b0, acc[1][nf], 0, 0, 0);
      acc[0][nf] = __builtin_amdgcn_mfma_f32_16x16x32_bf16(afr[0][1], b1, acc[0][nf], 0, 0, 0);
      acc[1][nf] = __builtin_amdgcn_mfma_f32_16x16x32_bf16(afr[1][1], b1, acc[1][nf], 0, 0, 0);
    }
  }

  // epilogue: bias + store into [n][k*4+d] layout
#pragma unroll
  for (int nf = 0; nf < 7; ++nf) {
    const int ch = 16 * nf + lr;
    if (ch < 108) {
      const float bv  = (ch < 81) ? b_off[ch] : b_mask[ch - 81];
      const int   pos = (ch < 81) ? ((ch / 3) * 4 + (ch % 3)) : ((ch - 81) * 4 + 3);
#pragma unroll
      for (int mf = 0; mf < 2; ++mf)
#pragma unroll
        for (int r = 0; r < 4; ++r) {
          const int row = n0 + 16 * mf + 4 * lg + r;
          convT[((size_t)b * NN + row) * OCT + pos] = acc[mf][nf][r] + bv;
        }
    }
  }
}

// ---------------------------------------------------------------------------
// Kernel 2: softmax over K=27 mask logits, convT[bn][4k+3], in place.
// ---------------------------------------------------------------------------
__global__ __launch_bounds__(256) void softmaxT_kernel(float* __restrict__ convT)
{
  const int i = blockIdx.x * 256 + threadIdx.x;   // 73728 exact
  float* p = convT + (size_t)i * OCT;

  float v[KK];
  float mx = -1e30f;
#pragma unroll
  for (int k = 0; k < KK; ++k) { v[k] = p[4 * k + 3]; mx = fmaxf(mx, v[k]); }
  float s = 0.f;
#pragma unroll
  for (int k = 0; k < KK; ++k) { v[k] = expf(v[k] - mx); s += v[k]; }
  const float inv = 1.f / s;
#pragma unroll
  for (int k = 0; k < KK; ++k) p[4 * k + 3] = v[k] * inv;
}

// ---------------------------------------------------------------------------
// Kernel 3: deformable gather (octet scheme) + MFMA tap-GEMM. No barriers.
// Wave = 32 positions (2 y-rows x 16 x). lane = (pos8, cinOct8).
// ---------------------------------------------------------------------------
__global__ __launch_bounds__(256) void deform_mfma_kernel(
    const bf16_t* __restrict__ xTbf, const float* __restrict__ convT,
    const bf16_t* __restrict__ wBd, const float* __restrict__ bias,
    float* __restrict__ out)
{
  const int bid  = (blockIdx.x % 8) * 72 + blockIdx.x / 8;   // XCD swizzle
  const int tid  = threadIdx.x;
  const int wid  = tid >> 6;
  const int lane = tid & 63;
  const int p8   = lane >> 3;     // position within octet
  const int q    = lane & 7;      // channel octet
  const int lr   = lane & 15;     // MFMA row/col
  const int lg   = lane >> 4;

  const int tile = bid * 4 + wid;           // 0..2303
  const int b    = tile / 576;
  const int rem  = tile % 576;
  const int z    = rem / 72;
  const int r2   = rem % 72;
  const int y0   = (r2 / 3) * 2;
  const int x0   = (r2 % 3) * 16;
  const int n0   = (z * WW + y0) * WW + x0;

  const float* cb = convT + ((size_t)b * NN + n0) * OCT;
  const unsigned short* xq =
      (const unsigned short*)(xTbf + (size_t)b * NN * CIN_) + (q << 3);

  __shared__ __align__(16) unsigned short S[4][32][64];
  unsigned short* Sw = &S[wid][0][0];
  unsigned int*  SwU = (unsigned int*)Sw;

  // per-lane constants for the 4 octets
  int   cOff[4];
  float pxb[4], pyb[4];
#pragma unroll
  for (int oct = 0; oct < 4; ++oct) {
    const int j  = oct * 8 + p8;
    const int jy = j >> 4;
    const int jx = j & 15;
    cOff[oct] = (jy * WW + jx) * OCT;
    pyb[oct]  = (float)(y0 + jy - 1);
    pxb[oct]  = (float)(x0 + jx - 1);
  }
  const float pzb = (float)(z - 1);

  f32x4 acc[2][4];
#pragma unroll
  for (int mf = 0; mf < 2; ++mf)
#pragma unroll
    for (int nf = 0; nf < 4; ++nf) acc[mf][nf] = (f32x4){0.f, 0.f, 0.f, 0.f};

#pragma unroll 1
  for (int k = 0; k < KK; ++k) {
    const int kz = k / 9;
    const int kr = k - kz * 9;
    const int ky = kr / 3;
    const int kx = kr - ky * 3;
    const float kzf = (float)kz, kyf = (float)ky, kxf = (float)kx;

    // ---- Phase A: gather 8 positions x 64 channels per octet ----
#pragma unroll
    for (int oct = 0; oct < 4; ++oct) {
      const int j = oct * 8 + p8;
      const f32x4 om = *(const f32x4*)(cb + cOff[oct] + 4 * k);

      const float pz = pzb + kzf + om.x;
      const float py = pyb[oct] + kyf + om.y;
      const float px = pxb[oct] + kxf + om.z;
      const float m  = om.w;

      const float zf = floorf(pz); const float fz = pz - zf; const int z0 = (int)zf;
      const float yf = floorf(py); const float fy = py - yf; const int y0i = (int)yf;
      const float xf = floorf(px); const float fx = px - xf; const int xi0 = (int)xf;

      const float wz0 = ((unsigned)z0        < DD) ? (1.f - fz) : 0.f;
      const float wz1 = ((unsigned)(z0 + 1)  < DD) ? fz         : 0.f;
      const float wy0 = ((unsigned)y0i       < HH) ? (1.f - fy) : 0.f;
      const float wy1 = ((unsigned)(y0i + 1) < HH) ? fy         : 0.f;
      const float wx0 = ((unsigned)xi0       < WW) ? (1.f - fx) : 0.f;
      const float wx1 = ((unsigned)(xi0 + 1) < WW) ? fx         : 0.f;

      const int z0c = min(max(z0, 0),      DD - 1);
      const int z1c = min(max(z0 + 1, 0),  DD - 1);
      const int y0c = min(max(y0i, 0),     HH - 1);
      const int y1c = min(max(y0i + 1, 0), HH - 1);
      const int x0c = min(max(xi0, 0),     WW - 1);
      const int x1c = min(max(xi0 + 1, 0), WW - 1);

      const int r00 = (z0c * HH + y0c) * WW;
      const int r01 = (z0c * HH + y1c) * WW;
      const int r10 = (z1c * HH + y0c) * WW;
      const int r11 = (z1c * HH + y1c) * WW;
      const float w00 = wz0 * wy0, w01 = wz0 * wy1;
      const float w10 = wz1 * wy0, w11 = wz1 * wy1;

      f32x2 a01 = {0.f, 0.f}, a23 = {0.f, 0.f}, a45 = {0.f, 0.f}, a67 = {0.f, 0.f};

#define CORNER(ROW, WGT)                                            \
      {                                                             \
        const u32x4 v = *(const u32x4*)(xq + ((size_t)(ROW) << 6)); \
        const float w_ = (WGT);                                     \
        a01 += (f32x2){bflo(v.x), bfhi(v.x)} * w_;                  \
        a23 += (f32x2){bflo(v.y), bfhi(v.y)} * w_;                  \
        a45 += (f32x2){bflo(v.z), bfhi(v.z)} * w_;                  \
        a67 += (f32x2){bflo(v.w), bfhi(v.w)} * w_;                  \
      }
      CORNER(r00 + x0c, w00 * wx0)
      CORNER(r00 + x1c, w00 * wx1)
      CORNER(r01 + x0c, w01 * wx0)
      CORNER(r01 + x1c, w01 * wx1)
      CORNER(r10 + x0c, w10 * wx0)
      CORNER(r10 + x1c, w10 * wx1)
      CORNER(r11 + x0c, w11 * wx0)
      CORNER(r11 + x1c, w11 * wx1)
#undef CORNER

      a01 *= m; a23 *= m; a45 *= m; a67 *= m;
      unsigned int d0, d1, d2, d3;
      asm("v_cvt_pk_bf16_f32 %0, %1, %2" : "=v"(d0) : "v"(a01.x), "v"(a01.y));
      asm("v_cvt_pk_bf16_f32 %0, %1, %2" : "=v"(d1) : "v"(a23.x), "v"(a23.y));
      asm("v_cvt_pk_bf16_f32 %0, %1, %2" : "=v"(d2) : "v"(a45.x), "v"(a45.y));
      asm("v_cvt_pk_bf16_f32 %0, %1, %2" : "=v"(d3) : "v"(a67.x), "v"(a67.y));
      const int slot = q ^ (j & 7);               // XOR-swizzle (T2)
      *(u32x4*)(SwU + j * 32 + slot * 4) = (u32x4){d0, d1, d2, d3};
    }

    // ---- Phase B: S[32x64] * W_k[64x64] via MFMA ----
    bf16x8 afr[2][2];
#pragma unroll
    for (int mf = 0; mf < 2; ++mf)
#pragma unroll
      for (int t = 0; t < 2; ++t) {
        const int row  = 16 * mf + lr;
        const int slot = (t * 4 + lg) ^ (row & 7);
        afr[mf][t] = *(const bf16x8*)(Sw + row * 64 + slot * 8);
      }
    const bf16_t* wk = wBd + (size_t)k * 4096 + lr * 64 + 8 * lg;
#pragma unroll
    for (int nf = 0; nf < 4; ++nf) {
      const bf16x8 b0 = *(const bf16x8*)(wk + nf * 1024);
      const bf16x8 b1 = *(const bf16x8*)(wk + nf * 1024 + 32);
      acc[0][nf] = __builtin_amdgcn_mfma_f32_16x16x32_bf16(afr[0][0], b0, acc[0][nf], 0, 0, 0);
      acc[1][nf] = __builtin_amdgcn_mfma_f32_16x16x32_bf16(afr[1][0], b0, acc[1][nf], 0, 0, 0);
      acc[0][nf] = __builtin_amdgcn_mfma_f32_16x16x32_bf16(afr[0][1], b1, acc[0][nf], 0, 0, 0);
      acc[1][nf] = __builtin_amdgcn_mfma_f32_16x16x32_bf16(afr[1][1], b1, acc[1][nf], 0, 0, 0);
    }
  }

  // epilogue: C/D row = pos offset 4*lg+r, col = cout = 16*nf+lr
#pragma unroll
  for (int nf = 0; nf < 4; ++nf) {
    const float bv = bias[16 * nf + lr];
    float* op = out + ((size_t)(b * COUT_ + 16 * nf + lr)) * NN + n0 + 4 * lg;
#pragma unroll
    for (int mf = 0; mf < 2; ++mf)
#pragma unroll
      for (int r = 0; r < 4; ++r)
        op[mf * WW + r] = acc[mf][nf][r] + bv;
  }
}

// ---------------------------------------------------------------------------
extern "C" void kernel_launch(void* const* d_in, const int* in_sizes, int n_in,
                              void* d_out, int out_size, void* d_ws, size_t ws_size,
                              hipStream_t stream)
{
  const float* x      = (const float*)d_in[0];
  const float* w_off  = (const float*)d_in[1];
  const float* b_off  = (const float*)d_in[2];
  const float* w_mask = (const float*)d_in[3];
  const float* b_mask = (const float*)d_in[4];
  const float* weight = (const float*)d_in[5];
  const float* bias   = (const float*)d_in[6];
  float* out = (float*)d_out;

  // Workspace (bytes):
  //   convT : B*N*108 fp32   = 31,850,496
  //   xTbf  : B*N*64  bf16   =  9,437,184
  //   wB    : 27*112*64 bf16 =    387,072
  //   wBd   : 27*64*64 bf16  =    221,184
  //   zp    : 128
  char* ws = (char*)d_ws;
  float*  convT = (float*)ws;
  bf16_t* xTbf  = (bf16_t*)(ws + 31850496);
  bf16_t* wB    = (bf16_t*)(ws + 31850496 + 9437184);
  bf16_t* wBd   = (bf16_t*)(ws + 31850496 + 9437184 + 387072);
  bf16_t* zp    = (bf16_t*)(ws + 31850496 + 9437184 + 387072 + 221184);

  zp_init_kernel<<<1, 64, 0, stream>>>(zp);
  dim3 gtx(NN / 64, B_);
  transpose_x_kernel<<<gtx, 256, 0, stream>>>(x, xTbf);
  wb_build_kernel<<<(KK * 112 * 64) / 256, 256, 0, stream>>>(w_off, w_mask, wB);
  wbd_build_kernel<<<(KK * CIN_ * COUT_) / 256, 256, 0, stream>>>(weight, wBd);

  conv108_mfma_kernel<<<576, 256, 0, stream>>>(xTbf, wB, b_off, b_mask, zp, convT);
  softmaxT_kernel<<<(B_ * NN) / 256, 256, 0, stream>>>(convT);
  deform_mfma_kernel<<<576, 256, 0, stream>>>(xTbf, convT, wBd, bias, out);
}